// Round 9
// baseline (253.098 us; speedup 1.0000x reference)
//
#include <hip/hip_runtime.h>

typedef unsigned short u16;
typedef unsigned int u32;
typedef unsigned long long u64;
typedef __attribute__((ext_vector_type(8))) short short8;
typedef __attribute__((ext_vector_type(4))) float f32x4;
typedef __attribute__((ext_vector_type(2))) float f32x2;
typedef __attribute__((ext_vector_type(4))) u32 u32x4;

__device__ __forceinline__ float b2f(u16 v) { return __uint_as_float(((u32)v) << 16); }
__device__ __forceinline__ u16 f2b(float f) {
  u32 x = __float_as_uint(f);
  return (u16)((x + 0x7FFFu + ((x >> 16) & 1u)) >> 16);  // round-nearest-even
}

// ---------------- runtime dtype detection (deterministic, graph-safe) ----------------
__global__ void detect_kernel(const u16* __restrict__ X16, const int* __restrict__ EIDX,
                              int* __restrict__ flags) {
  if (threadIdx.x != 0 || blockIdx.x != 0) return;
  int isb = 1;
  for (int i = 0; i < 32; i += 2) {
    const u16 v = X16[i];
    const u32 hb = (v >> 8) & 0x7f;
    if (!(v == 0 || (hb >= 0x32 && hb <= 0x41))) isb = 0;
  }
  int i64 = 1;
  for (int i = 1; i < 32; i += 2)
    if (EIDX[i] != 0) i64 = 0;
  flags[0] = isb;
  flags[1] = i64;
}

__global__ void sentinel_kernel(float* out) {
  if (threadIdx.x == 0 && blockIdx.x == 0) out[0] = 1.0e6f;  // ws too small marker
}

// ---------------- fused: h = X@W^T + b (MFMA) + edge rank, SW-pipelined --------------
// Every block: (1) issue its ~512 edges' atomicAdds FIRST, (2) full GEMM tile (the
// long MFMA/LDS phase hides the atomic round-trip), (3) store rank results last.
// No LDS-holding atomic-only blocks -> occupancy is gemm-limited again.
__global__ __launch_bounds__(256) void gemm_rank_kernel(
    const void* __restrict__ Xv, const void* __restrict__ Wv, const void* __restrict__ Bv,
    u16* __restrict__ H, int M, const int* __restrict__ EIDX, int* __restrict__ cnt,
    int* __restrict__ rank, int E, int NBG, int GRID, const int* __restrict__ flags) {
  const int isb = flags[0];
  const int i64 = flags[1];
  const int tid = threadIdx.x;
  const int bx = blockIdx.x;

  // ---- phase 1: issue edge atomics (results consumed in phase 3) ----
  const int e0 = bx * 256 + tid;
  const int e1 = e0 + GRID * 256;
  u32 r0 = 0, r1 = 0;
  if (e0 < E) {
    const int t = i64 ? EIDX[2 * E + 2 * e0] : EIDX[E + e0];
    r0 = atomicAdd(&cnt[t], 1);
  }
  if (e1 < E) {
    const int t = i64 ? EIDX[2 * E + 2 * e1] : EIDX[E + e1];
    r1 = atomicAdd(&cnt[t], 1);
  }

  // ---- phase 2: gemm tile (block-uniform branch; all NBG <= GRID blocks do it) ----
  __shared__ u16 lw[128 * 128];  // XOR chunk swizzle
  if (bx < NBG) {
    const int tile = bx;
    {
      const int row = tid >> 1, half = tid & 1;
      if (isb) {
        const u16* src = (const u16*)Wv + row * 128;
#pragma unroll
        for (int i = 0; i < 8; ++i) {
          const int c = half * 8 + i;
          *(short8*)&lw[row * 128 + ((c ^ (row & 15)) * 8)] = *(const short8*)(src + c * 8);
        }
      } else {
        const float* src = (const float*)Wv + row * 128;
#pragma unroll
        for (int i = 0; i < 8; ++i) {
          const int c = half * 8 + i;
          f32x4 a = *(const f32x4*)(src + c * 8);
          f32x4 b = *(const f32x4*)(src + c * 8 + 4);
          short8 o;
#pragma unroll
          for (int j = 0; j < 4; ++j) { o[j] = (short)f2b(a[j]); o[j + 4] = (short)f2b(b[j]); }
          *(short8*)&lw[row * 128 + ((c ^ (row & 15)) * 8)] = o;
        }
      }
    }
    __syncthreads();

    const int wave = tid >> 6, lane = tid & 63;
    const int q = lane >> 4, r = lane & 15;
    const int mfrag = tile * 64 + wave * 16 + r;  // A-frag: m = lane&15, k = q*8+j
    const long msafe = (mfrag < M) ? mfrag : 0;

    f32x4 acc[8];
#pragma unroll
    for (int i = 0; i < 8; ++i) acc[i] = (f32x4){0.f, 0.f, 0.f, 0.f};

#pragma unroll
    for (int kk = 0; kk < 4; ++kk) {
      short8 a;
      if (isb) {
        a = *(const short8*)((const u16*)Xv + msafe * 128 + kk * 32 + q * 8);
      } else {
        const float* xp = (const float*)Xv + msafe * 128 + kk * 32 + q * 8;
        f32x4 x0 = *(const f32x4*)xp;
        f32x4 x1 = *(const f32x4*)(xp + 4);
#pragma unroll
        for (int j = 0; j < 4; ++j) { a[j] = (short)f2b(x0[j]); a[j + 4] = (short)f2b(x1[j]); }
      }
#pragma unroll
      for (int nt = 0; nt < 8; ++nt) {
        short8 b = *(const short8*)&lw[(nt * 16 + r) * 128 + (((kk * 4 + q) ^ r) * 8)];
        acc[nt] = __builtin_amdgcn_mfma_f32_16x16x32_bf16(a, b, acc[nt], 0, 0, 0);
      }
    }

    const int mbase = tile * 64 + wave * 16 + q * 4;  // C/D: col=lane&15, row=q*4+reg
#pragma unroll
    for (int nt = 0; nt < 8; ++nt) {
      const int n = nt * 16 + r;
      const float bn = isb ? b2f(((const u16*)Bv)[n]) : ((const float*)Bv)[n];
#pragma unroll
      for (int rr = 0; rr < 4; ++rr) {
        const int m = mbase + rr;
        if (m < M) H[(long)m * 128 + n] = f2b(acc[nt][rr] + bn);
      }
    }
  }

  // ---- phase 3: store rank results (atomic returns have long since landed) ----
  if (e0 < E) rank[e0] = (int)r0;
  if (e1 < E) rank[e1] = (int)r1;
}

// ---------------- fused: per-(node,head) attention alphas + per-block cnt sums --------
__global__ __launch_bounds__(256) void alpha_bsums_kernel(
    const u16* __restrict__ H, const void* __restrict__ ATTv, float* __restrict__ ea_t,
    float* __restrict__ ea_s, int N, int NA, const int* __restrict__ cnt,
    int* __restrict__ bsum, const int* __restrict__ flags) {
  __shared__ int s[256];
  if ((int)blockIdx.x >= NA) {  // ---- bsums role ----
    const int bid = blockIdx.x - NA;
    const int i = bid * 256 + threadIdx.x;
    s[threadIdx.x] = (i < N) ? cnt[i] : 0;
    __syncthreads();
    for (int o = 128; o > 0; o >>= 1) {
      if (threadIdx.x < o) s[threadIdx.x] += s[threadIdx.x + o];
      __syncthreads();
    }
    if (threadIdx.x == 0) bsum[bid] = s[0];
    return;
  }
  // ---- alpha role ----
  const int isb = flags[0];
  const int tid = blockIdx.x * 256 + threadIdx.x;
  if (tid >= N * 4) return;
  const int node = tid >> 2, head = tid & 3;
  const u16* hp = H + (long)node * 128 + head * 32;
  const u16* a16 = (const u16*)ATTv + head * 64;
  const float* a32 = (const float*)ATTv + head * 64;
  float st = 0.f, ss = 0.f;
#pragma unroll
  for (int v = 0; v < 4; ++v) {
    short8 hv = *(const short8*)(hp + v * 8);
#pragma unroll
    for (int j = 0; j < 8; ++j) {
      const int k = v * 8 + j;
      const float x = b2f((u16)hv[j]);
      st += x * (isb ? b2f(a16[k]) : a32[k]);
      ss += x * (isb ? b2f(a16[32 + k]) : a32[32 + k]);
    }
  }
  ea_t[tid] = __expf(0.01f * st);
  ea_s[tid] = __expf(0.01f * ss);
}

// ---------------- scan_final with inlined block-base reduction (scan_scan merged) -----
__global__ __launch_bounds__(256) void scan_final(const int* __restrict__ cnt,
                                                  const int* __restrict__ bsum,
                                                  int* __restrict__ offsets, int N) {
  __shared__ int sb[256];
  __shared__ int s[256];
  const int bid = blockIdx.x;
  const int t = threadIdx.x;
  // base = sum of bsum[j], j < bid (raw per-block sums; ~391 ints, trivial)
  int partial = 0;
  for (int j = t; j < bid; j += 256) partial += bsum[j];
  sb[t] = partial;
  __syncthreads();
  for (int o = 128; o > 0; o >>= 1) {
    if (t < o) sb[t] += sb[t + o];
    __syncthreads();
  }
  const int base = sb[0];
  // intra-block exclusive scan of cnt
  const int i = bid * 256 + t;
  const int v = (i < N) ? cnt[i] : 0;
  s[t] = v;
  __syncthreads();
  for (int o = 1; o < 256; o <<= 1) {
    const int x = (t >= o) ? s[t - o] : 0;
    __syncthreads();
    s[t] += x;
    __syncthreads();
  }
  if (i < N) offsets[i] = s[t] - v + base;
}

// ---------------- bucket edges by target; materialize sorted src + ea ----------------
__global__ __launch_bounds__(256) void place_kernel(const int* __restrict__ EIDX,
                                                    const int* __restrict__ rank,
                                                    const int* __restrict__ offsets,
                                                    const float* __restrict__ ea_s,
                                                    int* __restrict__ s_src,
                                                    f32x4* __restrict__ s_ea, int E,
                                                    const int* __restrict__ flags) {
  const int i64 = flags[1];
  const int e = blockIdx.x * 256 + threadIdx.x;
  if (e >= E) return;
  const int s = i64 ? EIDX[2 * e] : EIDX[e];
  const int t = i64 ? EIDX[2 * E + 2 * e] : EIDX[E + e];
  const int pos = offsets[t] + rank[e];
  s_src[pos] = s;
  s_ea[pos] = *(const f32x4*)(ea_s + (size_t)s * 4);
}

// ---------------- per-node aggregation + head mean (quarter-wave, 4 edges/iter) ------
__global__ __launch_bounds__(512) void agg_kernel(const u16* __restrict__ H,
                                                  const int* __restrict__ s_src,
                                                  const float* __restrict__ s_ea,
                                                  const float* __restrict__ ea_t,
                                                  const int* __restrict__ offsets,
                                                  const int* __restrict__ cnt,
                                                  void* __restrict__ OUTv, int N,
                                                  const int* __restrict__ flags) {
  const int isb = flags[0];
  const int node = blockIdx.x * 8 + (threadIdx.x >> 6);
  if (node >= N) return;  // wave-uniform exit
  const int lane = threadIdx.x & 63;
  const int quarter = lane >> 4;  // which edge of the current 4
  const int sub = lane & 15;      // channels 8*sub .. 8*sub+7
  const int head = sub >> 2;      // lane-uniform head
  const int start = offsets[node];
  const int deg = cnt[node];

  float ac[8] = {0.f, 0.f, 0.f, 0.f, 0.f, 0.f, 0.f, 0.f};
  float s0 = 0.f;
  const int iters = (deg + 3) >> 2;
#pragma unroll 2
  for (int i = 0; i < iters; ++i) {
    const int eix = 4 * i + quarter;
    const bool valid = eix < deg;
    const u32 a = (u32)start + (valid ? (u32)eix : 0u);
    const int src = s_src[a];
    float ea = s_ea[a * 4u + head];
    if (!valid) ea = 0.f;
    const u32x4 hv = *(const u32x4*)(H + (u32)src * 128u + sub * 8u);
#pragma unroll
    for (int w = 0; w < 4; ++w) {
      ac[2 * w] += ea * b2f((u16)(hv[w] & 0xFFFFu));
      ac[2 * w + 1] += ea * b2f((u16)(hv[w] >> 16));
    }
    s0 += ea;
  }

#pragma unroll
  for (int w = 0; w < 8; ++w) {
    ac[w] += __shfl_xor(ac[w], 16);
    ac[w] += __shfl_xor(ac[w], 32);
  }
  s0 += __shfl_xor(s0, 16);
  s0 += __shfl_xor(s0, 32);

  const float et = ea_t[(u32)node * 4u + head];
  const float scale = 0.25f * et / (et * s0 + 1e-8f);  // softmax + 1/4 head mean
#pragma unroll
  for (int w = 0; w < 8; ++w) ac[w] *= scale;

#pragma unroll
  for (int w = 0; w < 8; ++w) {
    ac[w] += __shfl_xor(ac[w], 4);
    ac[w] += __shfl_xor(ac[w], 8);
  }

  if (lane < 4) {  // lane covers output channels 8*lane .. 8*lane+7
    if (isb) {
      u32x4 o;
#pragma unroll
      for (int w = 0; w < 4; ++w)
        o[w] = (u32)f2b(ac[2 * w]) | ((u32)f2b(ac[2 * w + 1]) << 16);
      *(u32x4*)((u16*)OUTv + (u32)node * 32 + lane * 8) = o;
    } else {
      float* op = (float*)OUTv + (u32)node * 32 + lane * 8;
      *(f32x4*)op = (f32x4){ac[0], ac[1], ac[2], ac[3]};
      *(f32x4*)(op + 4) = (f32x4){ac[4], ac[5], ac[6], ac[7]};
    }
  }
}

extern "C" void kernel_launch(void* const* d_in, const int* in_sizes, int n_in,
                              void* d_out, int out_size, void* d_ws, size_t ws_size,
                              hipStream_t stream) {
  const void* X = d_in[0];
  const int* EIDX = (const int*)d_in[1];
  const void* W = d_in[2];
  const void* B = d_in[3];
  const void* ATT = d_in[4];

  const int N = in_sizes[0] / 128;
  const int E = in_sizes[1] / 2;

  char* ws = (char*)d_ws;
  size_t off = 0;
  auto alloc = [&](size_t bytes) {
    void* p = ws + off;
    off += (bytes + 255) & ~(size_t)255;
    return p;
  };
  u16* H = (u16*)alloc((size_t)N * 128 * 2);       // 25.6 MB
  float* ea_t = (float*)alloc((size_t)N * 4 * 4);  // 1.6 MB
  float* ea_s = (float*)alloc((size_t)N * 4 * 4);  // 1.6 MB
  int* cnt = (int*)alloc((size_t)N * 4);           // 0.4 MB
  int* bsum = (int*)alloc(4096);
  int* offsets = (int*)alloc((size_t)N * 4);       // 0.4 MB
  int* rank = (int*)alloc((size_t)E * 4);          // 3.2 MB
  int* s_src = (int*)alloc((size_t)E * 4);         // 3.2 MB
  f32x4* s_ea = (f32x4*)alloc((size_t)E * 16);     // 12.8 MB
  int* flags = (int*)alloc(256);                   // total ~49 MB

  if (ws_size < off) {  // diagnostic path: absmax would show ~1e6, not NaN
    hipMemsetAsync(d_out, 0, (size_t)out_size * 2, stream);
    sentinel_kernel<<<1, 64, 0, stream>>>((float*)d_out);
    return;
  }

  hipMemsetAsync(cnt, 0, (size_t)N * 4, stream);
  detect_kernel<<<1, 64, 0, stream>>>((const u16*)X, EIDX, flags);

  const int NBG = (N + 63) / 64;
  const int GRID = (NBG > (E + 511) / 512) ? NBG : (E + 511) / 512;  // 2 edges/thread
  gemm_rank_kernel<<<GRID, 256, 0, stream>>>(X, W, B, H, N, EIDX, cnt, rank, E,
                                             NBG, GRID, flags);

  const int NA = (N * 4 + 255) / 256;
  const int nb = (N + 255) / 256;
  alpha_bsums_kernel<<<NA + nb, 256, 0, stream>>>(H, ATT, ea_t, ea_s, N, NA, cnt,
                                                  bsum, flags);
  scan_final<<<nb, 256, 0, stream>>>(cnt, bsum, offsets, N);
  place_kernel<<<(E + 255) / 256, 256, 0, stream>>>(EIDX, rank, offsets, ea_s,
                                                    s_src, s_ea, E, flags);
  agg_kernel<<<(N + 7) / 8, 512, 0, stream>>>(H, s_src, (const float*)s_ea, ea_t,
                                              offsets, cnt, d_out, N, flags);
}

// Round 10
// 251.144 us; speedup vs baseline: 1.0078x; 1.0078x over previous
//
#include <hip/hip_runtime.h>

typedef unsigned short u16;
typedef unsigned int u32;
typedef unsigned long long u64;
typedef __attribute__((ext_vector_type(8))) short short8;
typedef __attribute__((ext_vector_type(4))) float f32x4;
typedef __attribute__((ext_vector_type(4))) int i32x4;
typedef __attribute__((ext_vector_type(4))) u32 u32x4;

__device__ __forceinline__ float b2f(u16 v) { return __uint_as_float(((u32)v) << 16); }
__device__ __forceinline__ u16 f2b(float f) {
  u32 x = __float_as_uint(f);
  return (u16)((x + 0x7FFFu + ((x >> 16) & 1u)) >> 16);  // round-nearest-even
}
__device__ __forceinline__ u16 f2h(float f) {  // f32 -> f16 bits (v_cvt_f16_f32, RNE)
  _Float16 h = (_Float16)f;
  u16 b;
  __builtin_memcpy(&b, &h, 2);
  return b;
}
__device__ __forceinline__ float h2f(u16 b) {  // f16 bits -> f32 (v_cvt_f32_f16)
  _Float16 h;
  __builtin_memcpy(&h, &b, 2);
  return (float)h;
}

// ---------------- runtime dtype detection (deterministic, graph-safe) ----------------
__global__ void detect_kernel(const u16* __restrict__ X16, const int* __restrict__ EIDX,
                              int* __restrict__ flags) {
  if (threadIdx.x != 0 || blockIdx.x != 0) return;
  int isb = 1;
  for (int i = 0; i < 32; i += 2) {
    const u16 v = X16[i];
    const u32 hb = (v >> 8) & 0x7f;
    if (!(v == 0 || (hb >= 0x32 && hb <= 0x41))) isb = 0;
  }
  int i64 = 1;
  for (int i = 1; i < 32; i += 2)
    if (EIDX[i] != 0) i64 = 0;
  flags[0] = isb;
  flags[1] = i64;
}

__global__ void sentinel_kernel(float* out) {
  if (threadIdx.x == 0 && blockIdx.x == 0) out[0] = 1.0e6f;  // ws too small marker
}

// ------- fused: h = X@W^T + b (MFMA)  +  edge rank (pipelined)  +  alpha/ea ----------
// Phase order: stage W/ATT -> barrier -> ISSUE atomics (post-barrier, so the barrier
// drain can't eat them) -> MFMA K-loop + C-write (~25us, hides atomic round-trip) ->
// barrier -> per-(row,head) alpha from L1/L2-hot H -> store rank results.
__global__ __launch_bounds__(256) void gemm_rank_alpha_kernel(
    const void* __restrict__ Xv, const void* __restrict__ Wv, const void* __restrict__ Bv,
    const void* __restrict__ ATTv, u16* __restrict__ H, float* __restrict__ ea_t,
    float* __restrict__ ea_s, int M, const int* __restrict__ EIDX, int* __restrict__ cnt,
    int* __restrict__ rank, int E, int NBG, int GRID, const int* __restrict__ flags) {
  const int isb = flags[0];
  const int i64 = flags[1];
  const int tid = threadIdx.x;
  const int bx = blockIdx.x;

  __shared__ u16 lw[128 * 128];     // W tile, XOR chunk swizzle (bank-balanced B-frags)
  __shared__ float att_lds[256];    // att_line as f32: [head*64 + k], k<32 tgt, k>=32 src

  // ---- phase 0: stage W + ATT ----
  if (bx < NBG) {
    const int row = tid >> 1, half = tid & 1;
    if (isb) {
      const u16* src = (const u16*)Wv + row * 128;
#pragma unroll
      for (int i = 0; i < 8; ++i) {
        const int c = half * 8 + i;
        *(short8*)&lw[row * 128 + ((c ^ (row & 15)) * 8)] = *(const short8*)(src + c * 8);
      }
    } else {
      const float* src = (const float*)Wv + row * 128;
#pragma unroll
      for (int i = 0; i < 8; ++i) {
        const int c = half * 8 + i;
        f32x4 a = *(const f32x4*)(src + c * 8);
        f32x4 b = *(const f32x4*)(src + c * 8 + 4);
        short8 o;
#pragma unroll
        for (int j = 0; j < 4; ++j) { o[j] = (short)f2b(a[j]); o[j + 4] = (short)f2b(b[j]); }
        *(short8*)&lw[row * 128 + ((c ^ (row & 15)) * 8)] = o;
      }
    }
    if (tid < 64) {
#pragma unroll
      for (int j = 0; j < 4; ++j) {
        const int k = tid * 4 + j;
        att_lds[k] = isb ? b2f(((const u16*)ATTv)[k]) : ((const float*)ATTv)[k];
      }
    }
  }
  __syncthreads();

  // ---- phase 1: issue edge atomics AFTER the barrier (results consumed in phase 5) --
  const int e0 = bx * 256 + tid;
  const int e1 = e0 + GRID * 256;
  u32 r0 = 0, r1 = 0;
  if (e0 < E) {
    const int t = i64 ? EIDX[2 * E + 2 * e0] : EIDX[E + e0];
    r0 = atomicAdd(&cnt[t], 1);
  }
  if (e1 < E) {
    const int t = i64 ? EIDX[2 * E + 2 * e1] : EIDX[E + e1];
    r1 = atomicAdd(&cnt[t], 1);
  }

  // ---- phase 2: MFMA tile (no barriers inside -> atomics stay in flight) ----
  if (bx < NBG) {
    const int tile = bx;
    const int wave = tid >> 6, lane = tid & 63;
    const int q = lane >> 4, r = lane & 15;
    const int mfrag = tile * 64 + wave * 16 + r;  // A-frag: m = lane&15, k = q*8+j
    const long msafe = (mfrag < M) ? mfrag : 0;

    f32x4 acc[8];
#pragma unroll
    for (int i = 0; i < 8; ++i) acc[i] = (f32x4){0.f, 0.f, 0.f, 0.f};

#pragma unroll
    for (int kk = 0; kk < 4; ++kk) {
      short8 a;
      if (isb) {
        a = *(const short8*)((const u16*)Xv + msafe * 128 + kk * 32 + q * 8);
      } else {
        const float* xp = (const float*)Xv + msafe * 128 + kk * 32 + q * 8;
        f32x4 x0 = *(const f32x4*)xp;
        f32x4 x1 = *(const f32x4*)(xp + 4);
#pragma unroll
        for (int j = 0; j < 4; ++j) { a[j] = (short)f2b(x0[j]); a[j + 4] = (short)f2b(x1[j]); }
      }
#pragma unroll
      for (int nt = 0; nt < 8; ++nt) {
        short8 b = *(const short8*)&lw[(nt * 16 + r) * 128 + (((kk * 4 + q) ^ r) * 8)];
        acc[nt] = __builtin_amdgcn_mfma_f32_16x16x32_bf16(a, b, acc[nt], 0, 0, 0);
      }
    }

    const int mbase = tile * 64 + wave * 16 + q * 4;  // C/D: col=lane&15, row=q*4+reg
#pragma unroll
    for (int nt = 0; nt < 8; ++nt) {
      const int n = nt * 16 + r;
      const float bn = isb ? b2f(((const u16*)Bv)[n]) : ((const float*)Bv)[n];
#pragma unroll
      for (int rr = 0; rr < 4; ++rr) {
        const int m = mbase + rr;
        if (m < M) H[(long)m * 128 + n] = f2b(acc[nt][rr] + bn);
      }
    }
  }

  // ---- phase 3: make this block's H rows visible, then alpha from hot cache ----
  __threadfence_block();
  __syncthreads();

  // ---- phase 4: alpha: thread -> (row = bx*64 + tid>>2, head = tid&3) ----
  if (bx < NBG) {
    const int row = bx * 64 + (tid >> 2);
    if (row < M) {
      const int head = tid & 3;
      const u16* hp = H + (size_t)row * 128 + head * 32;
      float st = 0.f, ss = 0.f;
#pragma unroll
      for (int v = 0; v < 4; ++v) {
        short8 hv = *(const short8*)(hp + v * 8);
#pragma unroll
        for (int j = 0; j < 8; ++j) {
          const float x = b2f((u16)hv[j]);
          st += x * att_lds[head * 64 + v * 8 + j];
          ss += x * att_lds[head * 64 + 32 + v * 8 + j];
        }
      }
      ea_t[row * 4 + head] = __expf(0.01f * st);  // e<=emax => leaky slope 0.01; emax
      ea_s[row * 4 + head] = __expf(0.01f * ss);  // factor cancels in softmax (EPS ~4e-10)
    }
  }

  // ---- phase 5: store rank results (atomic returns landed under the MFMA phase) ----
  if (e0 < E) rank[e0] = (int)r0;
  if (e1 < E) rank[e1] = (int)r1;
}

// ---------------- self-sufficient exclusive scan of cnt -> offsets ----------------
// Block bid sums cnt[0 .. bid*256) itself (int4-strided, L2-resident, ~2us total),
// then intra-block scan. No bsums/scan_scan dispatches needed.
__global__ __launch_bounds__(256) void scan_offsets_kernel(const int* __restrict__ cnt,
                                                           int* __restrict__ offsets,
                                                           int N) {
  __shared__ int sb[256];
  __shared__ int s[256];
  const int bid = blockIdx.x;
  const int t = threadIdx.x;
  const int nq = bid * 64;  // int4 count covering cnt[0 .. bid*256)
  int partial = 0;
  const i32x4* c4 = (const i32x4*)cnt;
  for (int j = t; j < nq; j += 256) {
    const i32x4 v = c4[j];
    partial += v[0] + v[1] + v[2] + v[3];
  }
  sb[t] = partial;
  __syncthreads();
  for (int o = 128; o > 0; o >>= 1) {
    if (t < o) sb[t] += sb[t + o];
    __syncthreads();
  }
  const int base = sb[0];
  const int i = bid * 256 + t;
  const int v = (i < N) ? cnt[i] : 0;
  s[t] = v;
  __syncthreads();
  for (int o = 1; o < 256; o <<= 1) {
    const int x = (t >= o) ? s[t - o] : 0;
    __syncthreads();
    s[t] += x;
    __syncthreads();
  }
  if (i < N) offsets[i] = s[t] - v + base;
}

// -------- bucket edges by target: ONE packed 16 B record {src, ea x4 f16} ------------
__global__ __launch_bounds__(256) void place_kernel(const int* __restrict__ EIDX,
                                                    const int* __restrict__ rank,
                                                    const int* __restrict__ offsets,
                                                    const float* __restrict__ ea_s,
                                                    u32x4* __restrict__ rec, int E,
                                                    const int* __restrict__ flags) {
  const int i64 = flags[1];
  const int e = blockIdx.x * 256 + threadIdx.x;
  if (e >= E) return;
  const int s = i64 ? EIDX[2 * e] : EIDX[e];
  const int t = i64 ? EIDX[2 * E + 2 * e] : EIDX[E + e];
  const int pos = offsets[t] + rank[e];
  const f32x4 ea = *(const f32x4*)(ea_s + (size_t)s * 4);
  const u32 p01 = (u32)f2h(ea[0]) | ((u32)f2h(ea[1]) << 16);
  const u32 p23 = (u32)f2h(ea[2]) | ((u32)f2h(ea[3]) << 16);
  rec[pos] = (u32x4){(u32)s, p01, p23, 0u};  // single scattered sector per edge
}

// ---------------- per-node aggregation + head mean (quarter-wave, 4 edges/iter) ------
// out[t] = mean_h( ea_t*S1[h] / (ea_t*S0[h] + EPS) ).
// Wave per node; quarter (16 lanes) per edge; lane loads 16 B = 8 channels of the
// edge's 256 B H-row (head = sub>>2, lane-uniform). Edge metadata = one broadcast
// 16 B record per edge. 2 vmem instructions per edge-quarter.
__global__ __launch_bounds__(512) void agg_kernel(const u16* __restrict__ H,
                                                  const u32x4* __restrict__ rec,
                                                  const float* __restrict__ ea_t,
                                                  const int* __restrict__ offsets,
                                                  const int* __restrict__ cnt,
                                                  void* __restrict__ OUTv, int N,
                                                  const int* __restrict__ flags) {
  const int isb = flags[0];
  const int node = blockIdx.x * 8 + (threadIdx.x >> 6);
  if (node >= N) return;  // wave-uniform exit
  const int lane = threadIdx.x & 63;
  const int quarter = lane >> 4;  // which edge of the current 4
  const int sub = lane & 15;      // channels 8*sub .. 8*sub+7
  const int head = sub >> 2;      // lane-uniform head
  const int start = offsets[node];
  const int deg = cnt[node];

  float ac[8] = {0.f, 0.f, 0.f, 0.f, 0.f, 0.f, 0.f, 0.f};
  float s0 = 0.f;
  const int iters = (deg + 3) >> 2;
#pragma unroll 2
  for (int i = 0; i < iters; ++i) {
    const int eix = 4 * i + quarter;
    const bool valid = eix < deg;
    const u32 a = (u32)start + (valid ? (u32)eix : 0u);
    const u32x4 rv = rec[a];  // broadcast within the quarter: 1 sector
    const int src = (int)rv[0];
    const u32 pw = rv[1 + (head >> 1)];
    float ea = h2f((u16)((head & 1) ? (pw >> 16) : (pw & 0xFFFFu)));
    if (!valid) ea = 0.f;
    const u32x4 hv = *(const u32x4*)(H + (u32)src * 128u + sub * 8u);
#pragma unroll
    for (int w = 0; w < 4; ++w) {
      ac[2 * w] += ea * b2f((u16)(hv[w] & 0xFFFFu));
      ac[2 * w + 1] += ea * b2f((u16)(hv[w] >> 16));
    }
    s0 += ea;
  }

  // merge the 4 quarter edge-streams (disjoint edges, identical channel coverage)
#pragma unroll
  for (int w = 0; w < 8; ++w) {
    ac[w] += __shfl_xor(ac[w], 16);
    ac[w] += __shfl_xor(ac[w], 32);
  }
  s0 += __shfl_xor(s0, 16);
  s0 += __shfl_xor(s0, 32);

  const float et = ea_t[(u32)node * 4u + head];
  const float scale = 0.25f * et / (et * s0 + 1e-8f);  // softmax + 1/4 head mean
#pragma unroll
  for (int w = 0; w < 8; ++w) ac[w] *= scale;

  // sum over heads: within-head channel 8*(sub&3)+j at lanes sub, sub^4, sub^8, sub^12
#pragma unroll
  for (int w = 0; w < 8; ++w) {
    ac[w] += __shfl_xor(ac[w], 4);
    ac[w] += __shfl_xor(ac[w], 8);
  }

  if (lane < 4) {  // lane covers output channels 8*lane .. 8*lane+7
    if (isb) {
      u32x4 o;
#pragma unroll
      for (int w = 0; w < 4; ++w)
        o[w] = (u32)f2b(ac[2 * w]) | ((u32)f2b(ac[2 * w + 1]) << 16);
      *(u32x4*)((u16*)OUTv + (u32)node * 32 + lane * 8) = o;
    } else {
      float* op = (float*)OUTv + (u32)node * 32 + lane * 8;
      *(f32x4*)op = (f32x4){ac[0], ac[1], ac[2], ac[3]};
      *(f32x4*)(op + 4) = (f32x4){ac[4], ac[5], ac[6], ac[7]};
    }
  }
}

extern "C" void kernel_launch(void* const* d_in, const int* in_sizes, int n_in,
                              void* d_out, int out_size, void* d_ws, size_t ws_size,
                              hipStream_t stream) {
  const void* X = d_in[0];
  const int* EIDX = (const int*)d_in[1];
  const void* W = d_in[2];
  const void* B = d_in[3];
  const void* ATT = d_in[4];

  const int N = in_sizes[0] / 128;
  const int E = in_sizes[1] / 2;

  char* ws = (char*)d_ws;
  size_t off = 0;
  auto alloc = [&](size_t bytes) {
    void* p = ws + off;
    off += (bytes + 255) & ~(size_t)255;
    return p;
  };
  u16* H = (u16*)alloc((size_t)N * 128 * 2);       // 25.6 MB
  float* ea_t = (float*)alloc((size_t)N * 4 * 4);  // 1.6 MB
  float* ea_s = (float*)alloc((size_t)N * 4 * 4);  // 1.6 MB
  int* cnt = (int*)alloc((size_t)N * 4);           // 0.4 MB
  int* offsets = (int*)alloc((size_t)N * 4);       // 0.4 MB
  int* rank = (int*)alloc((size_t)E * 4);          // 3.2 MB
  u32x4* rec = (u32x4*)alloc((size_t)E * 16);      // 12.8 MB
  int* flags = (int*)alloc(256);                   // total ~46 MB

  if (ws_size < off) {  // diagnostic path: absmax would show ~1e6, not NaN
    hipMemsetAsync(d_out, 0, (size_t)out_size * 2, stream);
    sentinel_kernel<<<1, 64, 0, stream>>>((float*)d_out);
    return;
  }

  hipMemsetAsync(cnt, 0, (size_t)N * 4, stream);
  detect_kernel<<<1, 64, 0, stream>>>((const u16*)X, EIDX, flags);

  const int NBG = (N + 63) / 64;
  const int GE = (E + 511) / 512;  // 2 edges/thread
  const int GRID = (NBG > GE) ? NBG : GE;
  gemm_rank_alpha_kernel<<<GRID, 256, 0, stream>>>(X, W, B, ATT, H, ea_t, ea_s, N,
                                                   EIDX, cnt, rank, E, NBG, GRID, flags);

  const int nb = (N + 255) / 256;
  scan_offsets_kernel<<<nb, 256, 0, stream>>>(cnt, offsets, N);
  place_kernel<<<(E + 255) / 256, 256, 0, stream>>>(EIDX, rank, offsets, ea_s, rec,
                                                    E, flags);
  agg_kernel<<<(N + 7) / 8, 512, 0, stream>>>(H, rec, ea_t, offsets, cnt, d_out, N, flags);
}

// Round 11
// 241.633 us; speedup vs baseline: 1.0474x; 1.0394x over previous
//
#include <hip/hip_runtime.h>

typedef unsigned short u16;
typedef unsigned int u32;
typedef unsigned long long u64;
typedef __attribute__((ext_vector_type(8))) short short8;
typedef __attribute__((ext_vector_type(4))) float f32x4;
typedef __attribute__((ext_vector_type(4))) int i32x4;
typedef __attribute__((ext_vector_type(4))) u32 u32x4;

__device__ __forceinline__ float b2f(u16 v) { return __uint_as_float(((u32)v) << 16); }
__device__ __forceinline__ u16 f2b(float f) {
  u32 x = __float_as_uint(f);
  return (u16)((x + 0x7FFFu + ((x >> 16) & 1u)) >> 16);  // round-nearest-even
}
__device__ __forceinline__ u16 f2h(float f) {  // f32 -> f16 bits (RNE)
  _Float16 h = (_Float16)f;
  u16 b;
  __builtin_memcpy(&b, &h, 2);
  return b;
}
__device__ __forceinline__ float h2f(u16 b) {
  _Float16 h;
  __builtin_memcpy(&h, &b, 2);
  return (float)h;
}

// ---------------- runtime dtype detection (deterministic, graph-safe) ----------------
__global__ void detect_kernel(const u16* __restrict__ X16, const int* __restrict__ EIDX,
                              int* __restrict__ flags) {
  if (threadIdx.x != 0 || blockIdx.x != 0) return;
  int isb = 1;
  for (int i = 0; i < 32; i += 2) {
    const u16 v = X16[i];
    const u32 hb = (v >> 8) & 0x7f;
    if (!(v == 0 || (hb >= 0x32 && hb <= 0x41))) isb = 0;
  }
  int i64 = 1;
  for (int i = 1; i < 32; i += 2)
    if (EIDX[i] != 0) i64 = 0;
  flags[0] = isb;
  flags[1] = i64;
}

__global__ void sentinel_kernel(float* out) {
  if (threadIdx.x == 0 && blockIdx.x == 0) out[0] = 1.0e6f;  // ws too small marker
}

// ------- fused: h = X@W^T + b (MFMA) + edge rank (pipelined) + alpha/ea --------------
// 512 threads / 128 rows per block: same 32 KB W-tile serves 8 waves -> occupancy cap
// rises from LDS-bound 16 waves/CU to VGPR-bound ~24 waves/CU, and W staging traffic
// halves. Atomics issued AFTER the staging barrier ride under the MFMA phase.
__global__ __launch_bounds__(512) void gemm_rank_alpha_kernel(
    const void* __restrict__ Xv, const void* __restrict__ Wv, const void* __restrict__ Bv,
    const void* __restrict__ ATTv, u16* __restrict__ H, float* __restrict__ ea_t,
    float* __restrict__ ea_s, int M, const int* __restrict__ EIDX, int* __restrict__ cnt,
    int* __restrict__ rank, int E, int NBG, int GRID, const int* __restrict__ flags) {
  const int isb = flags[0];
  const int i64 = flags[1];
  const int tid = threadIdx.x;
  const int bx = blockIdx.x;

  __shared__ u16 lw[128 * 128];   // W tile, XOR chunk swizzle (bank-balanced B-frags)
  __shared__ float att_lds[256];  // att_line f32: [head*64 + k], k<32 tgt, k>=32 src

  // ---- phase 0: stage W (32 u16/thread) + ATT ----
  if (bx < NBG) {
    const int row = tid >> 2, qt = tid & 3;
    if (isb) {
      const u16* src = (const u16*)Wv + row * 128;
#pragma unroll
      for (int i = 0; i < 4; ++i) {
        const int c = qt * 4 + i;
        *(short8*)&lw[row * 128 + ((c ^ (row & 15)) * 8)] = *(const short8*)(src + c * 8);
      }
    } else {
      const float* src = (const float*)Wv + row * 128;
#pragma unroll
      for (int i = 0; i < 4; ++i) {
        const int c = qt * 4 + i;
        f32x4 a = *(const f32x4*)(src + c * 8);
        f32x4 b = *(const f32x4*)(src + c * 8 + 4);
        short8 o;
#pragma unroll
        for (int j = 0; j < 4; ++j) { o[j] = (short)f2b(a[j]); o[j + 4] = (short)f2b(b[j]); }
        *(short8*)&lw[row * 128 + ((c ^ (row & 15)) * 8)] = o;
      }
    }
    if (tid < 64) {
#pragma unroll
      for (int j = 0; j < 4; ++j) {
        const int k = tid * 4 + j;
        att_lds[k] = isb ? b2f(((const u16*)ATTv)[k]) : ((const float*)ATTv)[k];
      }
    }
  }
  __syncthreads();

  // ---- phase 1: issue edge atomics AFTER the barrier (consumed in phase 5) ----
  const int e0 = bx * 512 + tid;
  const int e1 = e0 + GRID * 512;
  u32 r0 = 0, r1 = 0;
  if (e0 < E) {
    const int t = i64 ? EIDX[2 * E + 2 * e0] : EIDX[E + e0];
    r0 = atomicAdd(&cnt[t], 1);
  }
  if (e1 < E) {
    const int t = i64 ? EIDX[2 * E + 2 * e1] : EIDX[E + e1];
    r1 = atomicAdd(&cnt[t], 1);
  }

  // ---- phase 2: MFMA tile (no barriers inside -> atomics stay in flight) ----
  if (bx < NBG) {
    const int wave = tid >> 6, lane = tid & 63;
    const int q = lane >> 4, r = lane & 15;
    const int mfrag = bx * 128 + wave * 16 + r;  // A-frag: m = lane&15, k = q*8+j
    const long msafe = (mfrag < M) ? mfrag : 0;

    f32x4 acc[8];
#pragma unroll
    for (int i = 0; i < 8; ++i) acc[i] = (f32x4){0.f, 0.f, 0.f, 0.f};

#pragma unroll
    for (int kk = 0; kk < 4; ++kk) {
      short8 a;
      if (isb) {
        a = *(const short8*)((const u16*)Xv + msafe * 128 + kk * 32 + q * 8);
      } else {
        const float* xp = (const float*)Xv + msafe * 128 + kk * 32 + q * 8;
        f32x4 x0 = *(const f32x4*)xp;
        f32x4 x1 = *(const f32x4*)(xp + 4);
#pragma unroll
        for (int j = 0; j < 4; ++j) { a[j] = (short)f2b(x0[j]); a[j + 4] = (short)f2b(x1[j]); }
      }
#pragma unroll
      for (int nt = 0; nt < 8; ++nt) {
        short8 b = *(const short8*)&lw[(nt * 16 + r) * 128 + (((kk * 4 + q) ^ r) * 8)];
        acc[nt] = __builtin_amdgcn_mfma_f32_16x16x32_bf16(a, b, acc[nt], 0, 0, 0);
      }
    }

    const int mbase = bx * 128 + wave * 16 + q * 4;  // C/D: col=lane&15, row=q*4+reg
#pragma unroll
    for (int nt = 0; nt < 8; ++nt) {
      const int n = nt * 16 + r;
      const float bn = isb ? b2f(((const u16*)Bv)[n]) : ((const float*)Bv)[n];
#pragma unroll
      for (int rr = 0; rr < 4; ++rr) {
        const int m = mbase + rr;
        if (m < M) H[(long)m * 128 + n] = f2b(acc[nt][rr] + bn);
      }
    }
  }

  // ---- phase 3: drain stores (barrier), then alpha from L2-hot H ----
  __threadfence_block();
  __syncthreads();

  // ---- phase 4: alpha: thread -> (row = bx*128 + tid>>2, head = tid&3) ----
  if (bx < NBG) {
    const int row = bx * 128 + (tid >> 2);
    if (row < M) {
      const int head = tid & 3;
      const u16* hp = H + (size_t)row * 128 + head * 32;
      float st = 0.f, ss = 0.f;
#pragma unroll
      for (int v = 0; v < 4; ++v) {
        short8 hv = *(const short8*)(hp + v * 8);
#pragma unroll
        for (int j = 0; j < 8; ++j) {
          const float x = b2f((u16)hv[j]);
          st += x * att_lds[head * 64 + v * 8 + j];
          ss += x * att_lds[head * 64 + 32 + v * 8 + j];
        }
      }
      ea_t[row * 4 + head] = __expf(0.01f * st);  // e<=emax => leaky slope 0.01; emax
      ea_s[row * 4 + head] = __expf(0.01f * ss);  // factor cancels in softmax (~4e-10)
    }
  }

  // ---- phase 5: store rank results (atomic returns landed under MFMA) ----
  if (e0 < E) rank[e0] = (int)r0;
  if (e1 < E) rank[e1] = (int)r1;
}

// ---------------- self-sufficient exclusive scan of cnt -> offsets ----------------
__global__ __launch_bounds__(256) void scan_offsets_kernel(const int* __restrict__ cnt,
                                                           int* __restrict__ offsets,
                                                           int N) {
  __shared__ int sb[256];
  __shared__ int s[256];
  const int bid = blockIdx.x;
  const int t = threadIdx.x;
  const int nq = bid * 64;  // int4 count covering cnt[0 .. bid*256)
  int partial = 0;
  const i32x4* c4 = (const i32x4*)cnt;
  for (int j = t; j < nq; j += 256) {
    const i32x4 v = c4[j];
    partial += v[0] + v[1] + v[2] + v[3];
  }
  sb[t] = partial;
  __syncthreads();
  for (int o = 128; o > 0; o >>= 1) {
    if (t < o) sb[t] += sb[t + o];
    __syncthreads();
  }
  const int base = sb[0];
  const int i = bid * 256 + t;
  const int v = (i < N) ? cnt[i] : 0;
  s[t] = v;
  __syncthreads();
  for (int o = 1; o < 256; o <<= 1) {
    const int x = (t >= o) ? s[t - o] : 0;
    __syncthreads();
    s[t] += x;
    __syncthreads();
  }
  if (i < N) offsets[i] = s[t] - v + base;
}

// -------- bucket edges by target: ONE packed 16 B record {src, ea x4 f16} ------------
__global__ __launch_bounds__(256) void place_kernel(const int* __restrict__ EIDX,
                                                    const int* __restrict__ rank,
                                                    const int* __restrict__ offsets,
                                                    const float* __restrict__ ea_s,
                                                    u32x4* __restrict__ rec, int E,
                                                    const int* __restrict__ flags) {
  const int i64 = flags[1];
  const int e = blockIdx.x * 256 + threadIdx.x;
  if (e >= E) return;
  const int s = i64 ? EIDX[2 * e] : EIDX[e];
  const int t = i64 ? EIDX[2 * E + 2 * e] : EIDX[E + e];
  const int pos = offsets[t] + rank[e];
  const f32x4 ea = *(const f32x4*)(ea_s + (size_t)s * 4);
  const u32 p01 = (u32)f2h(ea[0]) | ((u32)f2h(ea[1]) << 16);
  const u32 p23 = (u32)f2h(ea[2]) | ((u32)f2h(ea[3]) << 16);
  rec[pos] = (u32x4){(u32)s, p01, p23, 0u};  // single scattered sector per edge
}

// ---------------- per-node aggregation + head mean (quarter-wave, 4 edges/iter) ------
__global__ __launch_bounds__(512) void agg_kernel(const u16* __restrict__ H,
                                                  const u32x4* __restrict__ rec,
                                                  const float* __restrict__ ea_t,
                                                  const int* __restrict__ offsets,
                                                  const int* __restrict__ cnt,
                                                  void* __restrict__ OUTv, int N,
                                                  const int* __restrict__ flags) {
  const int isb = flags[0];
  const int node = blockIdx.x * 8 + (threadIdx.x >> 6);
  if (node >= N) return;  // wave-uniform exit
  const int lane = threadIdx.x & 63;
  const int quarter = lane >> 4;  // which edge of the current 4
  const int sub = lane & 15;      // channels 8*sub .. 8*sub+7
  const int head = sub >> 2;      // lane-uniform head
  const int start = offsets[node];
  const int deg = cnt[node];

  float ac[8] = {0.f, 0.f, 0.f, 0.f, 0.f, 0.f, 0.f, 0.f};
  float s0 = 0.f;
  const int iters = (deg + 3) >> 2;
#pragma unroll 2
  for (int i = 0; i < iters; ++i) {
    const int eix = 4 * i + quarter;
    const bool valid = eix < deg;
    const u32 a = (u32)start + (valid ? (u32)eix : 0u);
    const u32x4 rv = rec[a];  // broadcast within the quarter: 1 sector
    const int src = (int)rv[0];
    const u32 pw = rv[1 + (head >> 1)];
    float ea = h2f((u16)((head & 1) ? (pw >> 16) : (pw & 0xFFFFu)));
    if (!valid) ea = 0.f;
    const u32x4 hv = *(const u32x4*)(H + (u32)src * 128u + sub * 8u);
#pragma unroll
    for (int w = 0; w < 4; ++w) {
      ac[2 * w] += ea * b2f((u16)(hv[w] & 0xFFFFu));
      ac[2 * w + 1] += ea * b2f((u16)(hv[w] >> 16));
    }
    s0 += ea;
  }

  // merge the 4 quarter edge-streams (disjoint edges, identical channel coverage)
#pragma unroll
  for (int w = 0; w < 8; ++w) {
    ac[w] += __shfl_xor(ac[w], 16);
    ac[w] += __shfl_xor(ac[w], 32);
  }
  s0 += __shfl_xor(s0, 16);
  s0 += __shfl_xor(s0, 32);

  const float et = ea_t[(u32)node * 4u + head];
  const float scale = 0.25f * et / (et * s0 + 1e-8f);  // softmax + 1/4 head mean
#pragma unroll
  for (int w = 0; w < 8; ++w) ac[w] *= scale;

  // sum over heads: within-head channel 8*(sub&3)+j at lanes sub, sub^4, sub^8, sub^12
#pragma unroll
  for (int w = 0; w < 8; ++w) {
    ac[w] += __shfl_xor(ac[w], 4);
    ac[w] += __shfl_xor(ac[w], 8);
  }

  if (lane < 4) {  // lane covers output channels 8*lane .. 8*lane+7
    if (isb) {
      u32x4 o;
#pragma unroll
      for (int w = 0; w < 4; ++w)
        o[w] = (u32)f2b(ac[2 * w]) | ((u32)f2b(ac[2 * w + 1]) << 16);
      *(u32x4*)((u16*)OUTv + (u32)node * 32 + lane * 8) = o;
    } else {
      float* op = (float*)OUTv + (u32)node * 32 + lane * 8;
      *(f32x4*)op = (f32x4){ac[0], ac[1], ac[2], ac[3]};
      *(f32x4*)(op + 4) = (f32x4){ac[4], ac[5], ac[6], ac[7]};
    }
  }
}

extern "C" void kernel_launch(void* const* d_in, const int* in_sizes, int n_in,
                              void* d_out, int out_size, void* d_ws, size_t ws_size,
                              hipStream_t stream) {
  const void* X = d_in[0];
  const int* EIDX = (const int*)d_in[1];
  const void* W = d_in[2];
  const void* B = d_in[3];
  const void* ATT = d_in[4];

  const int N = in_sizes[0] / 128;
  const int E = in_sizes[1] / 2;

  char* ws = (char*)d_ws;
  size_t off = 0;
  auto alloc = [&](size_t bytes) {
    void* p = ws + off;
    off += (bytes + 255) & ~(size_t)255;
    return p;
  };
  u16* H = (u16*)alloc((size_t)N * 128 * 2);       // 25.6 MB
  float* ea_t = (float*)alloc((size_t)N * 4 * 4);  // 1.6 MB
  float* ea_s = (float*)alloc((size_t)N * 4 * 4);  // 1.6 MB
  int* cnt = (int*)alloc((size_t)N * 4);           // 0.4 MB
  int* offsets = (int*)alloc((size_t)N * 4);       // 0.4 MB
  int* rank = (int*)alloc((size_t)E * 4);          // 3.2 MB
  u32x4* rec = (u32x4*)alloc((size_t)E * 16);      // 12.8 MB
  int* flags = (int*)alloc(256);                   // total ~46 MB

  if (ws_size < off) {  // diagnostic path: absmax would show ~1e6, not NaN
    hipMemsetAsync(d_out, 0, (size_t)out_size * 2, stream);
    sentinel_kernel<<<1, 64, 0, stream>>>((float*)d_out);
    return;
  }

  hipMemsetAsync(cnt, 0, (size_t)N * 4, stream);
  detect_kernel<<<1, 64, 0, stream>>>((const u16*)X, EIDX, flags);

  const int NBG = (N + 127) / 128;
  const int GE = (E + 1023) / 1024;  // 2 edges/thread at 512 threads
  const int GRID = (NBG > GE) ? NBG : GE;
  gemm_rank_alpha_kernel<<<GRID, 512, 0, stream>>>(X, W, B, ATT, H, ea_t, ea_s, N,
                                                   EIDX, cnt, rank, E, NBG, GRID, flags);

  const int nb = (N + 255) / 256;
  scan_offsets_kernel<<<nb, 256, 0, stream>>>(cnt, offsets, N);
  place_kernel<<<(E + 255) / 256, 256, 0, stream>>>(EIDX, rank, offsets, ea_s, rec,
                                                    E, flags);
  agg_kernel<<<(N + 7) / 8, 512, 0, stream>>>(H, rec, ea_t, offsets, cnt, d_out, N, flags);
}